// Round 6
// baseline (878.471 us; speedup 1.0000x reference)
//
#include <hip/hip_runtime.h>
#include <cstdint>

#define T_TOK 1024
#define HID   2048
#define NEXP  64
#define TOPK  8
#define INTER 768

typedef __attribute__((ext_vector_type(8))) short short8;   // 8 x bf16
typedef __attribute__((ext_vector_type(4))) float f32x4;
typedef __attribute__((ext_vector_type(2))) unsigned int uint2v;

__device__ __forceinline__ unsigned short f2bf(float f){
  unsigned u = __float_as_uint(f);
  u += 0x7FFFu + ((u >> 16) & 1u);   // RNE
  return (unsigned short)(u >> 16);
}

#define LDSA(p) ((unsigned)(uintptr_t)(__attribute__((address_space(3))) void*)(p))

__device__ __forceinline__ uint2v tr0(unsigned a){
  uint2v r; asm volatile("ds_read_b64_tr_b16 %0, %1" : "=v"(r) : "v"(a)); return r;
}
__device__ __forceinline__ uint2v tr512(unsigned a){
  uint2v r; asm volatile("ds_read_b64_tr_b16 %0, %1 offset:512" : "=v"(r) : "v"(a)); return r;
}
__device__ __forceinline__ short8 mkfrag(uint2v lo, uint2v hi){
  union { unsigned u[4]; short8 s; } v;
  v.u[0] = lo[0]; v.u[1] = lo[1]; v.u[2] = hi[0]; v.u[3] = hi[1];
  return v.s;
}

#define TRWAIT() do { asm volatile("s_waitcnt lgkmcnt(0)" ::: "memory"); \
                      __builtin_amdgcn_sched_barrier(0); } while (0)
#define BARRIER() do { asm volatile("s_waitcnt lgkmcnt(0)" ::: "memory"); \
                       __builtin_amdgcn_s_barrier(); } while (0)

// ---------------- kernel 1: x (fp32) -> bf16 once per launch ----------------
__global__ void k_convert_x(const float* __restrict__ x, unsigned short* __restrict__ xbf){
  int gid = blockIdx.x * 256 + threadIdx.x;
  const float4* src = (const float4*)(x + (size_t)gid * 8);
  float4 a = src[0], b = src[1];
  uint4 p;
  p.x = f2bf(a.x) | ((unsigned)f2bf(a.y) << 16);
  p.y = f2bf(a.z) | ((unsigned)f2bf(a.w) << 16);
  p.z = f2bf(b.x) | ((unsigned)f2bf(b.y) << 16);
  p.w = f2bf(b.z) | ((unsigned)f2bf(b.w) << 16);
  *(uint4*)(xbf + (size_t)gid * 8) = p;
}

// ---------------- kernel 2: router (fp32-exact logits, top-8) ----------------
__global__ void k_router(const float* __restrict__ x, const float* __restrict__ gw,
                         int* __restrict__ top_idx, float* __restrict__ top_w){
  int t = blockIdx.x;
  int tid = threadIdx.x;
  __shared__ float  xs[HID];
  __shared__ double part[4][NEXP];
  for (int i = tid; i < HID; i += 256) xs[i] = x[(size_t)t * HID + i];
  __syncthreads();
  int e = tid & 63, q = tid >> 6;
  double acc = 0.0;
  const float* gp = gw + e;
  #pragma unroll 8
  for (int h = q * 512; h < q * 512 + 512; ++h)
    acc += (double)xs[h] * (double)gp[(size_t)h * NEXP];
  part[q][e] = acc;
  __syncthreads();
  if (tid < 64){
    float logit = (float)(part[0][e] + part[1][e] + part[2][e] + part[3][e]);
    float cur = logit;
    float vals[TOPK]; int idxs[TOPK];
    #pragma unroll
    for (int k = 0; k < TOPK; ++k){
      float m = cur; int mi = e;
      #pragma unroll
      for (int off = 32; off > 0; off >>= 1){
        float ov = __shfl_xor(m, off);
        int   oi = __shfl_xor(mi, off);
        if (ov > m || (ov == m && oi < mi)){ m = ov; mi = oi; }
      }
      vals[k] = m; idxs[k] = mi;
      if (e == mi) cur = -1e30f;
    }
    float mx = vals[0], s = 0.f, ev[TOPK];
    #pragma unroll
    for (int k = 0; k < TOPK; ++k){ ev[k] = expf(vals[k] - mx); s += ev[k]; }
    #pragma unroll
    for (int k = 0; k < TOPK; ++k)
      if (e == k){ top_idx[t * TOPK + k] = idxs[k]; top_w[t * TOPK + k] = ev[k] / s; }
  }
}

// ---------------- kernel 3: per-expert histogram + exclusive scan ----------------
__global__ void k_hist(const int* __restrict__ top_idx, int* __restrict__ offs){
  __shared__ int hist[NEXP];
  int tid = threadIdx.x;
  if (tid < NEXP) hist[tid] = 0;
  __syncthreads();
  for (int j = tid; j < T_TOK * TOPK; j += 256) atomicAdd(&hist[top_idx[j]], 1);
  __syncthreads();
  if (tid == 0){
    int run = 0;
    for (int e = 0; e < NEXP; ++e){ offs[e] = run; run += hist[e]; }
    offs[NEXP] = run;
  }
}

// ---------------- kernel 4: deterministic ordered compaction ----------------
__global__ void k_compact(const int* __restrict__ top_idx, const float* __restrict__ top_w,
                          const int* __restrict__ offs, int* __restrict__ list_t,
                          float* __restrict__ list_w, int* __restrict__ slot_of){
  int e = blockIdx.x, tid = threadIdx.x;
  __shared__ int sc[256];
  int j0 = tid * 32, cnt = 0;
  for (int jj = 0; jj < 32; ++jj) cnt += (top_idx[j0 + jj] == e);
  sc[tid] = cnt; __syncthreads();
  for (int d = 1; d < 256; d <<= 1){
    int v = (tid >= d) ? sc[tid - d] : 0;
    __syncthreads();
    sc[tid] += v;
    __syncthreads();
  }
  int pos = offs[e] + sc[tid] - cnt;
  for (int jj = 0; jj < 32; ++jj){
    int j = j0 + jj;
    if (top_idx[j] == e){
      list_t[pos]  = j >> 3;
      list_w[pos]  = top_w[j];
      slot_of[j]   = pos;
      ++pos;
    }
  }
}

// ---------------- kernel 5: gate/up GEMM + SwiGLU ----------------
// 256 thr = 4 waves m-split (48 rows each), BM=192, BN=16, BK=64, KT=32.
// B: float4 (dwordx4) coalesced load -> bf16 pack -> linear ds_write_b64 into
// [64k][16c] panel; fragments via ds_read_b64_tr_b16 (HW transpose).
// A: global b64 pairs with matching k-permutation (k = ks*32 + {4q..4q+3, 16+4q..+3}).
__global__ __launch_bounds__(256) void k_gateup(
    const unsigned short* __restrict__ xbf, const float* __restrict__ wg,
    const float* __restrict__ wu, const int* __restrict__ offs,
    const int* __restrict__ list_t, const float* __restrict__ list_w,
    unsigned short* __restrict__ act){
  const int KT = 32;
  int e  = blockIdx.y;
  int i0 = blockIdx.x * 16;
  int beg = offs[e], n_e = offs[e + 1] - beg;
  if (n_e <= 0) return;
  int tid = threadIdx.x, lane = tid & 63, wid = tid >> 6;
  int cL = lane & 15, qL = lane >> 4;

  __shared__ unsigned short lB[2][2][64 * 16];   // [buf][mat][k*16+c], 8 KB
  __shared__ int   sTok[192];
  __shared__ float sWgt[192];

  int bk = tid >> 2, bc = (tid & 3) * 4;         // stage: k-row, col quad
  const float* gS = wg + ((size_t)e * HID + bk) * INTER + i0 + bc;
  const float* uS = wu + ((size_t)e * HID + bk) * INTER + i0 + bc;
  unsigned rAddr = LDSA(&lB[0][0][0]) + (unsigned)lane * 8;

#define GU_ISSUE_B(T, bs_) { \
    bs_[0] = *(const float4*)(gS + (size_t)(T) * 64 * INTER); \
    bs_[1] = *(const float4*)(uS + (size_t)(T) * 64 * INTER); }

#define GU_WRITE_B(BUF, bs_) { \
    uint2v _p; \
    _p[0] = f2bf(bs_[0].x) | ((unsigned)f2bf(bs_[0].y) << 16); \
    _p[1] = f2bf(bs_[0].z) | ((unsigned)f2bf(bs_[0].w) << 16); \
    *(uint2v*)&lB[BUF][0][bk * 16 + bc] = _p; \
    _p[0] = f2bf(bs_[1].x) | ((unsigned)f2bf(bs_[1].y) << 16); \
    _p[1] = f2bf(bs_[1].z) | ((unsigned)f2bf(bs_[1].w) << 16); \
    *(uint2v*)&lB[BUF][1][bk * 16 + bc] = _p; }

#define GU_ISSUE_A(T, ra_) { \
    _Pragma("unroll") for (int mf = 0; mf < 3; ++mf){ \
      const unsigned short* _ap = xbf + (size_t)tokA[mf] * HID + (T) * 64 + 4 * qL; \
      _Pragma("unroll") for (int ks = 0; ks < 2; ++ks){ \
        uint2v _lo = *(const uint2v*)(_ap + ks * 32); \
        uint2v _hi = *(const uint2v*)(_ap + ks * 32 + 16); \
        ra_[mf][ks] = mkfrag(_lo, _hi); } } }

#define GU_MFMA(BUF, ra_) { \
    _Pragma("unroll") for (int ks = 0; ks < 2; ++ks){ \
      unsigned _b = rAddr + (BUF) * 4096 + ks * 1024; \
      uint2v _g1 = tr0(_b),        _g2 = tr512(_b); \
      uint2v _u1 = tr0(_b + 2048), _u2 = tr512(_b + 2048); \
      TRWAIT(); \
      short8 _fg = mkfrag(_g1, _g2), _fu = mkfrag(_u1, _u2); \
      _Pragma("unroll") for (int mf = 0; mf < 3; ++mf){ \
        accg[mf] = __builtin_amdgcn_mfma_f32_16x16x32_bf16(ra_[mf][ks], _fg, accg[mf], 0, 0, 0); \
        accu[mf] = __builtin_amdgcn_mfma_f32_16x16x32_bf16(ra_[mf][ks], _fu, accu[mf], 0, 0, 0); } } }

  for (int m0 = 0; m0 < n_e; m0 += 192){
    __syncthreads();
    if (tid < 192){
      int sl = beg + m0 + tid;
      if (m0 + tid < n_e){ sTok[tid] = list_t[sl]; sWgt[tid] = list_w[sl]; }
      else               { sTok[tid] = list_t[beg]; sWgt[tid] = 0.f; }
    }
    __syncthreads();
    int tokA[3];
    #pragma unroll
    for (int mf = 0; mf < 3; ++mf) tokA[mf] = sTok[wid * 48 + mf * 16 + cL];

    float4 bs0[2], bs1[2];
    short8 rA0[3][2], rA1[3][2];
    f32x4 accg[3] = {}; f32x4 accu[3] = {};

    GU_ISSUE_A(0, rA0);
    GU_ISSUE_B(0, bs0);
    GU_ISSUE_B(1, bs1);
    GU_WRITE_B(0, bs0);
    BARRIER();

    #pragma unroll 1
    for (int t = 0; t < KT; t += 2){
      // even body: reads buf0 = B(t); A(t+1), B(t+2) in flight across barrier
      if (t + 1 < KT) GU_ISSUE_A(t + 1, rA1);
      if (t + 2 < KT) GU_ISSUE_B(t + 2, bs0);
      GU_MFMA(0, rA0);
      if (t + 1 < KT) GU_WRITE_B(1, bs1);
      BARRIER();
      // odd body: reads buf1 = B(t+1)
      if (t + 2 < KT) GU_ISSUE_A(t + 2, rA0);
      if (t + 3 < KT) GU_ISSUE_B(t + 3, bs1);
      GU_MFMA(1, rA1);
      if (t + 2 < KT) GU_WRITE_B(0, bs0);
      BARRIER();
    }

    // epilogue: SwiGLU * routing weight -> bf16
    #pragma unroll
    for (int mf = 0; mf < 3; ++mf){
      #pragma unroll
      for (int rr = 0; rr < 4; ++rr){
        int r = wid * 48 + mf * 16 + qL * 4 + rr;
        if (m0 + r < n_e){
          int slot = beg + m0 + r;
          float wgt = sWgt[r];
          float g = accg[mf][rr], u = accu[mf][rr];
          float h = (g / (1.f + expf(-g))) * u * wgt;
          act[(size_t)slot * INTER + i0 + cL] = f2bf(h);
        }
      }
    }
  }
}

// ---------------- kernel 6: down-proj GEMM ----------------
// 256 thr = 4 waves x 48 rows, BM=192, BN=32 (2 panels), BK=64, KT=12.
__global__ __launch_bounds__(256) void k_down(
    const unsigned short* __restrict__ act, const float* __restrict__ wd,
    const int* __restrict__ offs, const int* __restrict__ list_t,
    float* __restrict__ contrib, float* __restrict__ out, int atomicMode){
  const int KT = 12;
  int e  = blockIdx.y;
  int n0 = blockIdx.x * 32;
  int beg = offs[e], n_e = offs[e + 1] - beg;
  if (n_e <= 0) return;
  int tid = threadIdx.x, lane = tid & 63, wid = tid >> 6;
  int cL = lane & 15, qL = lane >> 4;

  __shared__ unsigned short lB[2][2][64 * 16];   // [buf][panel][k*16+c], 8 KB
  __shared__ int sTok[192];

  int bk = tid >> 3, bc = (tid & 7) * 4;         // k-row (0..31, x2 rounds), col quad
  const float* dS = wd + ((size_t)e * INTER + bk) * HID + n0 + bc;
  int wpan = bc >> 4, wcc = bc & 15;
  unsigned rAddr = LDSA(&lB[0][0][0]) + (unsigned)lane * 8;

#define DN_ISSUE_B(T, bs_) { \
    bs_[0] = *(const float4*)(dS + (size_t)(T) * 64 * HID); \
    bs_[1] = *(const float4*)(dS + (size_t)((T) * 64 + 32) * HID); }

#define DN_WRITE_B(BUF, bs_) { \
    uint2v _p; \
    _p[0] = f2bf(bs_[0].x) | ((unsigned)f2bf(bs_[0].y) << 16); \
    _p[1] = f2bf(bs_[0].z) | ((unsigned)f2bf(bs_[0].w) << 16); \
    *(uint2v*)&lB[BUF][wpan][bk * 16 + wcc] = _p; \
    _p[0] = f2bf(bs_[1].x) | ((unsigned)f2bf(bs_[1].y) << 16); \
    _p[1] = f2bf(bs_[1].z) | ((unsigned)f2bf(bs_[1].w) << 16); \
    *(uint2v*)&lB[BUF][wpan][(bk + 32) * 16 + wcc] = _p; }

#define DN_ISSUE_A(T, ra_) { \
    _Pragma("unroll") for (int mf = 0; mf < 3; ++mf){ \
      const unsigned short* _ap = act + (size_t)aslot[mf] * INTER + (T) * 64 + 4 * qL; \
      _Pragma("unroll") for (int ks = 0; ks < 2; ++ks){ \
        uint2v _lo = *(const uint2v*)(_ap + ks * 32); \
        uint2v _hi = *(const uint2v*)(_ap + ks * 32 + 16); \
        ra_[mf][ks] = mkfrag(_lo, _hi); } } }

#define DN_MFMA(BUF, ra_) { \
    _Pragma("unroll") for (int ks = 0; ks < 2; ++ks){ \
      unsigned _b = rAddr + (BUF) * 4096 + ks * 1024; \
      uint2v _a1 = tr0(_b),        _a2 = tr512(_b); \
      uint2v _b1 = tr0(_b + 2048), _b2 = tr512(_b + 2048); \
      TRWAIT(); \
      short8 _f0 = mkfrag(_a1, _a2), _f1 = mkfrag(_b1, _b2); \
      _Pragma("unroll") for (int mf = 0; mf < 3; ++mf){ \
        acc[mf][0] = __builtin_amdgcn_mfma_f32_16x16x32_bf16(ra_[mf][ks], _f0, acc[mf][0], 0, 0, 0); \
        acc[mf][1] = __builtin_amdgcn_mfma_f32_16x16x32_bf16(ra_[mf][ks], _f1, acc[mf][1], 0, 0, 0); } } }

  for (int m0 = 0; m0 < n_e; m0 += 192){
    __syncthreads();
    if (tid < 192){
      int sl = beg + m0 + tid;
      sTok[tid] = (m0 + tid < n_e) ? list_t[sl] : 0;
    }
    __syncthreads();
    int aslot[3];
    #pragma unroll
    for (int mf = 0; mf < 3; ++mf){
      int r = wid * 48 + mf * 16 + cL;
      aslot[mf] = (m0 + r < n_e) ? (beg + m0 + r) : beg;
    }
    float4 bs0[2], bs1[2];
    short8 rA0[3][2], rA1[3][2];
    f32x4 acc[3][2] = {};

    DN_ISSUE_A(0, rA0);
    DN_ISSUE_B(0, bs0);
    DN_ISSUE_B(1, bs1);
    DN_WRITE_B(0, bs0);
    BARRIER();

    #pragma unroll 1
    for (int t = 0; t < KT; t += 2){
      if (t + 1 < KT) DN_ISSUE_A(t + 1, rA1);
      if (t + 2 < KT) DN_ISSUE_B(t + 2, bs0);
      DN_MFMA(0, rA0);
      if (t + 1 < KT) DN_WRITE_B(1, bs1);
      BARRIER();
      if (t + 2 < KT) DN_ISSUE_A(t + 2, rA0);
      if (t + 3 < KT) DN_ISSUE_B(t + 3, bs1);
      DN_MFMA(1, rA1);
      if (t + 2 < KT) DN_WRITE_B(0, bs0);
      BARRIER();
    }

    #pragma unroll
    for (int mf = 0; mf < 3; ++mf){
      #pragma unroll
      for (int rr = 0; rr < 4; ++rr){
        int r = wid * 48 + mf * 16 + qL * 4 + rr;
        if (m0 + r < n_e){
          int slot = beg + m0 + r;
          #pragma unroll
          for (int nf = 0; nf < 2; ++nf){
            float v = acc[mf][nf][rr];
            int h = n0 + nf * 16 + cL;
            if (atomicMode) atomicAdd(&out[(size_t)sTok[r] * HID + h], v);
            else            contrib[(size_t)slot * HID + h] = v;
          }
        }
      }
    }
  }
}

// ---------------- kernel 7: deterministic 8-way combine ----------------
__global__ void k_reduce(const float* __restrict__ contrib, const int* __restrict__ slot_of,
                         float* __restrict__ out){
  int bx = blockIdx.x;
  int t = bx >> 1, seg = bx & 1, tid = threadIdx.x;
  __shared__ int ss[TOPK];
  if (tid < TOPK) ss[tid] = slot_of[t * TOPK + tid];
  __syncthreads();
  int h = (seg * 256 + tid) * 4;
  f32x4 s = {0.f, 0.f, 0.f, 0.f};
  #pragma unroll
  for (int k = 0; k < TOPK; ++k){
    f32x4 v = *(const f32x4*)(contrib + (size_t)ss[k] * HID + h);
    s += v;
  }
  *(f32x4*)(out + (size_t)t * HID + h) = s;
}

extern "C" void kernel_launch(void* const* d_in, const int* in_sizes, int n_in,
                              void* d_out, int out_size, void* d_ws, size_t ws_size,
                              hipStream_t stream){
  const float* x   = (const float*)d_in[0];
  const float* gw  = (const float*)d_in[1];
  const float* wgp = (const float*)d_in[2];
  const float* wup = (const float*)d_in[3];
  const float* wdp = (const float*)d_in[4];
  float* out = (float*)d_out;
  char* ws = (char*)d_ws;

  int*   top_idx = (int*)  (ws + 0);
  float* top_w   = (float*)(ws + 32768);
  int*   offs    = (int*)  (ws + 65536);
  int*   list_t  = (int*)  (ws + 69632);
  float* list_w  = (float*)(ws + 102400);
  int*   slot_of = (int*)  (ws + 135168);
  unsigned short* xbf = (unsigned short*)(ws + 167936);             // 4 MB
  unsigned short* act = (unsigned short*)(ws + 167936 + 4194304);   // 12 MB
  float* contrib = (float*)(ws + 167936 + 4194304 + 12582912);      // 64 MB
  size_t need_full = (size_t)167936 + 4194304 + 12582912 + 67108864;
  int atomicMode = (ws_size < need_full) ? 1 : 0;

  k_convert_x<<<1024, 256, 0, stream>>>(x, xbf);
  k_router   <<<1024, 256, 0, stream>>>(x, gw, top_idx, top_w);
  k_hist     <<<1,    256, 0, stream>>>(top_idx, offs);
  k_compact  <<<64,   256, 0, stream>>>(top_idx, top_w, offs, list_t, list_w, slot_of);
  k_gateup   <<<dim3(INTER / 16, NEXP), 256, 0, stream>>>(xbf, wgp, wup, offs, list_t, list_w, act);
  if (atomicMode){
    hipMemsetAsync(d_out, 0, (size_t)out_size * sizeof(float), stream);
    k_down  <<<dim3(HID / 32, NEXP), 256, 0, stream>>>(act, wdp, offs, list_t, contrib, out, 1);
  } else {
    k_down  <<<dim3(HID / 32, NEXP), 256, 0, stream>>>(act, wdp, offs, list_t, contrib, out, 0);
    k_reduce<<<2048, 256, 0, stream>>>(contrib, slot_of, out);
  }
}

// Round 7
// 520.095 us; speedup vs baseline: 1.6891x; 1.6891x over previous
//
#include <hip/hip_runtime.h>
#include <cstdint>

#define T_TOK 1024
#define HID   2048
#define NEXP  64
#define TOPK  8
#define INTER 768

typedef __attribute__((ext_vector_type(8))) short short8;   // 8 x bf16
typedef __attribute__((ext_vector_type(4))) float f32x4;
typedef __attribute__((ext_vector_type(2))) unsigned int uint2v;

__device__ __forceinline__ unsigned short f2bf(float f){
  unsigned u = __float_as_uint(f);
  u += 0x7FFFu + ((u >> 16) & 1u);   // RNE
  return (unsigned short)(u >> 16);
}

#define LDSA(p) ((unsigned)(uintptr_t)(__attribute__((address_space(3))) void*)(p))

// hardware transpose read, literal byte offset
#define TRRD(D, A, IMM) asm volatile("ds_read_b64_tr_b16 %0, %1 offset:" #IMM \
                                     : "=v"(D) : "v"(A))

__device__ __forceinline__ short8 mkfrag(uint2v lo, uint2v hi){
  union { unsigned u[4]; short8 s; } v;
  v.u[0] = lo[0]; v.u[1] = lo[1]; v.u[2] = hi[0]; v.u[3] = hi[1];
  return v.s;
}

#define TRWAIT() do { asm volatile("s_waitcnt lgkmcnt(0)" ::: "memory"); \
                      __builtin_amdgcn_sched_barrier(0); } while (0)
#define BARRIER() do { asm volatile("s_waitcnt lgkmcnt(0)" ::: "memory"); \
                       __builtin_amdgcn_s_barrier(); } while (0)

// ---------------- kernel 1: x (fp32) -> bf16 once per launch ----------------
__global__ void k_convert_x(const float* __restrict__ x, unsigned short* __restrict__ xbf){
  int gid = blockIdx.x * 256 + threadIdx.x;
  const float4* src = (const float4*)(x + (size_t)gid * 8);
  float4 a = src[0], b = src[1];
  uint4 p;
  p.x = f2bf(a.x) | ((unsigned)f2bf(a.y) << 16);
  p.y = f2bf(a.z) | ((unsigned)f2bf(a.w) << 16);
  p.z = f2bf(b.x) | ((unsigned)f2bf(b.y) << 16);
  p.w = f2bf(b.z) | ((unsigned)f2bf(b.w) << 16);
  *(uint4*)(xbf + (size_t)gid * 8) = p;
}

// ---------------- kernel 2: router (fp32-exact logits, top-8) ----------------
__global__ void k_router(const float* __restrict__ x, const float* __restrict__ gw,
                         int* __restrict__ top_idx, float* __restrict__ top_w){
  int t = blockIdx.x;
  int tid = threadIdx.x;
  __shared__ float  xs[HID];
  __shared__ double part[4][NEXP];
  for (int i = tid; i < HID; i += 256) xs[i] = x[(size_t)t * HID + i];
  __syncthreads();
  int e = tid & 63, q = tid >> 6;
  double acc = 0.0;
  const float* gp = gw + e;
  #pragma unroll 8
  for (int h = q * 512; h < q * 512 + 512; ++h)
    acc += (double)xs[h] * (double)gp[(size_t)h * NEXP];
  part[q][e] = acc;
  __syncthreads();
  if (tid < 64){
    float logit = (float)(part[0][e] + part[1][e] + part[2][e] + part[3][e]);
    float cur = logit;
    float vals[TOPK]; int idxs[TOPK];
    #pragma unroll
    for (int k = 0; k < TOPK; ++k){
      float m = cur; int mi = e;
      #pragma unroll
      for (int off = 32; off > 0; off >>= 1){
        float ov = __shfl_xor(m, off);
        int   oi = __shfl_xor(mi, off);
        if (ov > m || (ov == m && oi < mi)){ m = ov; mi = oi; }
      }
      vals[k] = m; idxs[k] = mi;
      if (e == mi) cur = -1e30f;
    }
    float mx = vals[0], s = 0.f, ev[TOPK];
    #pragma unroll
    for (int k = 0; k < TOPK; ++k){ ev[k] = expf(vals[k] - mx); s += ev[k]; }
    #pragma unroll
    for (int k = 0; k < TOPK; ++k)
      if (e == k){ top_idx[t * TOPK + k] = idxs[k]; top_w[t * TOPK + k] = ev[k] / s; }
  }
}

// ---------------- kernel 3: per-expert histogram + exclusive scan ----------------
__global__ void k_hist(const int* __restrict__ top_idx, int* __restrict__ offs){
  __shared__ int hist[NEXP];
  int tid = threadIdx.x;
  if (tid < NEXP) hist[tid] = 0;
  __syncthreads();
  for (int j = tid; j < T_TOK * TOPK; j += 256) atomicAdd(&hist[top_idx[j]], 1);
  __syncthreads();
  if (tid == 0){
    int run = 0;
    for (int e = 0; e < NEXP; ++e){ offs[e] = run; run += hist[e]; }
    offs[NEXP] = run;
  }
}

// ---------------- kernel 4: deterministic ordered compaction ----------------
__global__ void k_compact(const int* __restrict__ top_idx, const float* __restrict__ top_w,
                          const int* __restrict__ offs, int* __restrict__ list_t,
                          float* __restrict__ list_w, int* __restrict__ slot_of){
  int e = blockIdx.x, tid = threadIdx.x;
  __shared__ int sc[256];
  int j0 = tid * 32, cnt = 0;
  for (int jj = 0; jj < 32; ++jj) cnt += (top_idx[j0 + jj] == e);
  sc[tid] = cnt; __syncthreads();
  for (int d = 1; d < 256; d <<= 1){
    int v = (tid >= d) ? sc[tid - d] : 0;
    __syncthreads();
    sc[tid] += v;
    __syncthreads();
  }
  int pos = offs[e] + sc[tid] - cnt;
  for (int jj = 0; jj < 32; ++jj){
    int j = j0 + jj;
    if (top_idx[j] == e){
      list_t[pos]  = j >> 3;
      list_w[pos]  = top_w[j];
      slot_of[j]   = pos;
      ++pos;
    }
  }
}

// ---------------- kernel 5: gate/up GEMM + SwiGLU ----------------
// 256 thr = 4 waves m-split (48 rows each). BM=192, BN=32 x {gate,up}, BK=32, KT=64.
// B: per-lane float4 (128-B coalesced segments) -> bf16 -> b64 writes into
// [32k][16c] panels; fragments via ds_read_b64_tr_b16 off one base reg (R6-validated).
// A: k-permuted b64 pairs from global. Pipeline: A 2-deep, B 3-deep, raw barriers.
__global__ __launch_bounds__(256) void k_gateup(
    const unsigned short* __restrict__ xbf, const float* __restrict__ wg,
    const float* __restrict__ wu, const int* __restrict__ offs,
    const int* __restrict__ list_t, const float* __restrict__ list_w,
    unsigned short* __restrict__ act){
  int e  = blockIdx.y;
  int i0 = blockIdx.x * 32;
  int beg = offs[e], n_e = offs[e + 1] - beg;
  if (n_e <= 0) return;
  int tid = threadIdx.x, lane = tid & 63, wid = tid >> 6;
  int cL = lane & 15, qL = lane >> 4;

  __shared__ unsigned short lB[2][2][2][512];   // [buf][mat][panel][32k x 16c] = 8 KB
  __shared__ int   sTok[192];
  __shared__ float sWgt[192];

  int krow = tid >> 3, c4 = (tid & 7) << 2;     // stage: k-row 0..31, col quad
  int pan = c4 >> 4, cin = c4 & 15;
  unsigned wOff = (unsigned)(pan * 1024 + krow * 32 + cin * 2);   // bytes within (buf,mat)
  char* ldsC = (char*)&lB[0][0][0][0];
  unsigned rB = LDSA(&lB[0][0][0][0]) + (unsigned)lane * 8;
  const float* gB = wg + (size_t)e * HID * INTER + i0 + c4;
  const float* uB = wu + (size_t)e * HID * INTER + i0 + c4;

#define GU_ISSUE_B(T, S) { \
    bs[S][0] = *(const float4*)(gB + (size_t)((T) * 32 + krow) * INTER); \
    bs[S][1] = *(const float4*)(uB + (size_t)((T) * 32 + krow) * INTER); }

#define GU_WRITE_B(BUF, S) { \
    uint2v _p; \
    _p[0] = f2bf(bs[S][0].x) | ((unsigned)f2bf(bs[S][0].y) << 16); \
    _p[1] = f2bf(bs[S][0].z) | ((unsigned)f2bf(bs[S][0].w) << 16); \
    *(uint2v*)(ldsC + (BUF) * 4096 + wOff) = _p; \
    _p[0] = f2bf(bs[S][1].x) | ((unsigned)f2bf(bs[S][1].y) << 16); \
    _p[1] = f2bf(bs[S][1].z) | ((unsigned)f2bf(bs[S][1].w) << 16); \
    *(uint2v*)(ldsC + (BUF) * 4096 + 2048 + wOff) = _p; }

#define GU_ISSUE_A(T, S) { \
    _Pragma("unroll") for (int mf = 0; mf < 3; ++mf){ \
      const unsigned short* _ap = xbf + (size_t)tokA[mf] * HID + (T) * 32 + 4 * qL; \
      rA[S][mf] = mkfrag(*(const uint2v*)_ap, *(const uint2v*)(_ap + 16)); } }

#define GU_MFMA(BUF, AS) { \
    unsigned _b = rB + (BUF) * 4096; \
    uint2v _t0,_t1,_t2,_t3,_t4,_t5,_t6,_t7; \
    TRRD(_t0, _b, 0);    TRRD(_t1, _b, 512); \
    TRRD(_t2, _b, 1024); TRRD(_t3, _b, 1536); \
    TRRD(_t4, _b, 2048); TRRD(_t5, _b, 2560); \
    TRRD(_t6, _b, 3072); TRRD(_t7, _b, 3584); \
    TRWAIT(); \
    short8 _g0 = mkfrag(_t0,_t1), _g1 = mkfrag(_t2,_t3); \
    short8 _u0 = mkfrag(_t4,_t5), _u1 = mkfrag(_t6,_t7); \
    _Pragma("unroll") for (int mf = 0; mf < 3; ++mf){ \
      accg[mf][0] = __builtin_amdgcn_mfma_f32_16x16x32_bf16(rA[AS][mf], _g0, accg[mf][0], 0, 0, 0); \
      accg[mf][1] = __builtin_amdgcn_mfma_f32_16x16x32_bf16(rA[AS][mf], _g1, accg[mf][1], 0, 0, 0); \
      accu[mf][0] = __builtin_amdgcn_mfma_f32_16x16x32_bf16(rA[AS][mf], _u0, accu[mf][0], 0, 0, 0); \
      accu[mf][1] = __builtin_amdgcn_mfma_f32_16x16x32_bf16(rA[AS][mf], _u1, accu[mf][1], 0, 0, 0); } }

// body: A(t+1) first (A-drain keeps younger B alive), B(t+3), MFMA(t), write B(t+1).
#define GU_BODY(TT, K, DOA, DOB, DOW) { \
    if (DOA) GU_ISSUE_A((TT) + 1, ((K) + 1) & 1); \
    if (DOB) GU_ISSUE_B((TT) + 3, (K) % 3); \
    GU_MFMA((K) & 1, (K) & 1); \
    if (DOW) GU_WRITE_B(((K) + 1) & 1, ((K) + 1) % 3); \
    BARRIER(); }

  for (int m0 = 0; m0 < n_e; m0 += 192){
    __syncthreads();
    if (tid < 192){
      int sl = beg + m0 + tid;
      if (m0 + tid < n_e){ sTok[tid] = list_t[sl]; sWgt[tid] = list_w[sl]; }
      else               { sTok[tid] = list_t[beg]; sWgt[tid] = 0.f; }
    }
    __syncthreads();
    int tokA[3];
    #pragma unroll
    for (int mf = 0; mf < 3; ++mf) tokA[mf] = sTok[wid * 48 + mf * 16 + cL];

    float4 bs[3][2];
    short8 rA[2][3];
    f32x4 accg[3][2] = {}; f32x4 accu[3][2] = {};

    GU_ISSUE_A(0, 0);
    GU_ISSUE_B(0, 0); GU_ISSUE_B(1, 1); GU_ISSUE_B(2, 2);
    GU_WRITE_B(0, 0);                     // waits A0+B0; B1,B2 stay in flight
    BARRIER();

    #pragma unroll 1
    for (int t = 0; t < 60; t += 6){
      GU_BODY(t + 0, 0, 1, 1, 1);
      GU_BODY(t + 1, 1, 1, 1, 1);
      GU_BODY(t + 2, 2, 1, 1, 1);
      GU_BODY(t + 3, 3, 1, 1, 1);
      GU_BODY(t + 4, 4, 1, 1, 1);
      GU_BODY(t + 5, 5, 1, 1, 1);
    }
    GU_BODY(60, 0, 1, 1, 1);              // A61, B63, W61
    GU_BODY(61, 1, 1, 0, 1);              // A62, W62
    GU_BODY(62, 2, 1, 0, 1);              // A63, W63
    GU_BODY(63, 3, 0, 0, 0);              // MFMA only

    // epilogue: SwiGLU * routing weight -> bf16
    #pragma unroll
    for (int mf = 0; mf < 3; ++mf){
      #pragma unroll
      for (int rr = 0; rr < 4; ++rr){
        int r = wid * 48 + mf * 16 + qL * 4 + rr;
        if (m0 + r < n_e){
          int slot = beg + m0 + r;
          float wgt = sWgt[r];
          #pragma unroll
          for (int nf = 0; nf < 2; ++nf){
            float g = accg[mf][nf][rr], u = accu[mf][nf][rr];
            float h = (g / (1.f + expf(-g))) * u * wgt;
            act[(size_t)slot * INTER + i0 + nf * 16 + cL] = f2bf(h);
          }
        }
      }
    }
  }
}

// ---------------- kernel 6: down-proj GEMM ----------------
// 256 thr = 4 waves x 48 rows. BM=192, BN=64 (4 panels), BK=32, KT=24.
__global__ __launch_bounds__(256) void k_down(
    const unsigned short* __restrict__ act, const float* __restrict__ wd,
    const int* __restrict__ offs, const int* __restrict__ list_t,
    float* __restrict__ contrib, float* __restrict__ out, int atomicMode){
  int e  = blockIdx.y;
  int n0 = blockIdx.x * 64;
  int beg = offs[e], n_e = offs[e + 1] - beg;
  if (n_e <= 0) return;
  int tid = threadIdx.x, lane = tid & 63, wid = tid >> 6;
  int cL = lane & 15, qL = lane >> 4;

  __shared__ unsigned short lB[2][4][512];      // [buf][panel][32k x 16c] = 8 KB
  __shared__ int sTok[192];

  int krow = tid >> 3, c4 = (tid & 7) << 2;     // cols c4 and c4+32
  int pan = c4 >> 4, cin = c4 & 15;
  unsigned wOff = (unsigned)(pan * 1024 + krow * 32 + cin * 2);
  char* ldsC = (char*)&lB[0][0][0];
  unsigned rB = LDSA(&lB[0][0][0]) + (unsigned)lane * 8;
  const float* dB = wd + (size_t)e * INTER * HID + n0 + c4;

#define DN_ISSUE_B(T, S) { \
    bs[S][0] = *(const float4*)(dB + (size_t)((T) * 32 + krow) * HID); \
    bs[S][1] = *(const float4*)(dB + (size_t)((T) * 32 + krow) * HID + 32); }

#define DN_WRITE_B(BUF, S) { \
    uint2v _p; \
    _p[0] = f2bf(bs[S][0].x) | ((unsigned)f2bf(bs[S][0].y) << 16); \
    _p[1] = f2bf(bs[S][0].z) | ((unsigned)f2bf(bs[S][0].w) << 16); \
    *(uint2v*)(ldsC + (BUF) * 4096 + wOff) = _p; \
    _p[0] = f2bf(bs[S][1].x) | ((unsigned)f2bf(bs[S][1].y) << 16); \
    _p[1] = f2bf(bs[S][1].z) | ((unsigned)f2bf(bs[S][1].w) << 16); \
    *(uint2v*)(ldsC + (BUF) * 4096 + 2048 + wOff) = _p; }

#define DN_ISSUE_A(T, S) { \
    _Pragma("unroll") for (int mf = 0; mf < 3; ++mf){ \
      const unsigned short* _ap = act + (size_t)aslot[mf] * INTER + (T) * 32 + 4 * qL; \
      rA[S][mf] = mkfrag(*(const uint2v*)_ap, *(const uint2v*)(_ap + 16)); } }

#define DN_MFMA(BUF, AS) { \
    unsigned _b = rB + (BUF) * 4096; \
    uint2v _t0,_t1,_t2,_t3,_t4,_t5,_t6,_t7; \
    TRRD(_t0, _b, 0);    TRRD(_t1, _b, 512); \
    TRRD(_t2, _b, 1024); TRRD(_t3, _b, 1536); \
    TRRD(_t4, _b, 2048); TRRD(_t5, _b, 2560); \
    TRRD(_t6, _b, 3072); TRRD(_t7, _b, 3584); \
    TRWAIT(); \
    short8 _f0 = mkfrag(_t0,_t1), _f1 = mkfrag(_t2,_t3); \
    short8 _f2 = mkfrag(_t4,_t5), _f3 = mkfrag(_t6,_t7); \
    _Pragma("unroll") for (int mf = 0; mf < 3; ++mf){ \
      acc[mf][0] = __builtin_amdgcn_mfma_f32_16x16x32_bf16(rA[AS][mf], _f0, acc[mf][0], 0, 0, 0); \
      acc[mf][1] = __builtin_amdgcn_mfma_f32_16x16x32_bf16(rA[AS][mf], _f1, acc[mf][1], 0, 0, 0); \
      acc[mf][2] = __builtin_amdgcn_mfma_f32_16x16x32_bf16(rA[AS][mf], _f2, acc[mf][2], 0, 0, 0); \
      acc[mf][3] = __builtin_amdgcn_mfma_f32_16x16x32_bf16(rA[AS][mf], _f3, acc[mf][3], 0, 0, 0); } }

#define DN_BODY(TT, K, DOA, DOB, DOW) { \
    if (DOA) DN_ISSUE_A((TT) + 1, ((K) + 1) & 1); \
    if (DOB) DN_ISSUE_B((TT) + 3, (K) % 3); \
    DN_MFMA((K) & 1, (K) & 1); \
    if (DOW) DN_WRITE_B(((K) + 1) & 1, ((K) + 1) % 3); \
    BARRIER(); }

  for (int m0 = 0; m0 < n_e; m0 += 192){
    __syncthreads();
    if (tid < 192){
      int sl = beg + m0 + tid;
      sTok[tid] = (m0 + tid < n_e) ? list_t[sl] : 0;
    }
    __syncthreads();
    int aslot[3];
    #pragma unroll
    for (int mf = 0; mf < 3; ++mf){
      int r = wid * 48 + mf * 16 + cL;
      aslot[mf] = (m0 + r < n_e) ? (beg + m0 + r) : beg;
    }
    float4 bs[3][2];
    short8 rA[2][3];
    f32x4 acc[3][4] = {};

    DN_ISSUE_A(0, 0);
    DN_ISSUE_B(0, 0); DN_ISSUE_B(1, 1); DN_ISSUE_B(2, 2);
    DN_WRITE_B(0, 0);
    BARRIER();

    #pragma unroll 1
    for (int t = 0; t < 18; t += 6){
      DN_BODY(t + 0, 0, 1, 1, 1);
      DN_BODY(t + 1, 1, 1, 1, 1);
      DN_BODY(t + 2, 2, 1, 1, 1);
      DN_BODY(t + 3, 3, 1, 1, 1);
      DN_BODY(t + 4, 4, 1, 1, 1);
      DN_BODY(t + 5, 5, 1, 1, 1);
    }
    DN_BODY(18, 0, 1, 1, 1);
    DN_BODY(19, 1, 1, 1, 1);
    DN_BODY(20, 2, 1, 1, 1);              // B23 (last)
    DN_BODY(21, 3, 1, 0, 1);
    DN_BODY(22, 4, 1, 0, 1);              // W23 (last)
    DN_BODY(23, 5, 0, 0, 0);

    #pragma unroll
    for (int mf = 0; mf < 3; ++mf){
      #pragma unroll
      for (int rr = 0; rr < 4; ++rr){
        int r = wid * 48 + mf * 16 + qL * 4 + rr;
        if (m0 + r < n_e){
          int slot = beg + m0 + r;
          #pragma unroll
          for (int nf = 0; nf < 4; ++nf){
            float v = acc[mf][nf][rr];
            int h = n0 + nf * 16 + cL;
            if (atomicMode) atomicAdd(&out[(size_t)sTok[r] * HID + h], v);
            else            contrib[(size_t)slot * HID + h] = v;
          }
        }
      }
    }
  }
}

// ---------------- kernel 7: deterministic 8-way combine ----------------
__global__ void k_reduce(const float* __restrict__ contrib, const int* __restrict__ slot_of,
                         float* __restrict__ out){
  int bx = blockIdx.x;
  int t = bx >> 1, seg = bx & 1, tid = threadIdx.x;
  __shared__ int ss[TOPK];
  if (tid < TOPK) ss[tid] = slot_of[t * TOPK + tid];
  __syncthreads();
  int h = (seg * 256 + tid) * 4;
  f32x4 s = {0.f, 0.f, 0.f, 0.f};
  #pragma unroll
  for (int k = 0; k < TOPK; ++k){
    f32x4 v = *(const f32x4*)(contrib + (size_t)ss[k] * HID + h);
    s += v;
  }
  *(f32x4*)(out + (size_t)t * HID + h) = s;
}

extern "C" void kernel_launch(void* const* d_in, const int* in_sizes, int n_in,
                              void* d_out, int out_size, void* d_ws, size_t ws_size,
                              hipStream_t stream){
  const float* x   = (const float*)d_in[0];
  const float* gw  = (const float*)d_in[1];
  const float* wgp = (const float*)d_in[2];
  const float* wup = (const float*)d_in[3];
  const float* wdp = (const float*)d_in[4];
  float* out = (float*)d_out;
  char* ws = (char*)d_ws;

  int*   top_idx = (int*)  (ws + 0);
  float* top_w   = (float*)(ws + 32768);
  int*   offs    = (int*)  (ws + 65536);
  int*   list_t  = (int*)  (ws + 69632);
  float* list_w  = (float*)(ws + 102400);
  int*   slot_of = (int*)  (ws + 135168);
  unsigned short* xbf = (unsigned short*)(ws + 167936);             // 4 MB
  unsigned short* act = (unsigned short*)(ws + 167936 + 4194304);   // 12 MB
  float* contrib = (float*)(ws + 167936 + 4194304 + 12582912);      // 64 MB
  size_t need_full = (size_t)167936 + 4194304 + 12582912 + 67108864;
  int atomicMode = (ws_size < need_full) ? 1 : 0;

  k_convert_x<<<1024, 256, 0, stream>>>(x, xbf);
  k_router   <<<1024, 256, 0, stream>>>(x, gw, top_idx, top_w);
  k_hist     <<<1,    256, 0, stream>>>(top_idx, offs);
  k_compact  <<<64,   256, 0, stream>>>(top_idx, top_w, offs, list_t, list_w, slot_of);
  k_gateup   <<<dim3(INTER / 32, NEXP), 256, 0, stream>>>(xbf, wgp, wup, offs, list_t, list_w, act);
  if (atomicMode){
    hipMemsetAsync(d_out, 0, (size_t)out_size * sizeof(float), stream);
    k_down  <<<dim3(HID / 64, NEXP), 256, 0, stream>>>(act, wdp, offs, list_t, contrib, out, 1);
  } else {
    k_down  <<<dim3(HID / 64, NEXP), 256, 0, stream>>>(act, wdp, offs, list_t, contrib, out, 0);
    k_reduce<<<2048, 256, 0, stream>>>(contrib, slot_of, out);
  }
}